// Round 2
// baseline (563.308 us; speedup 1.0000x reference)
//
#include <hip/hip_runtime.h>
#include <math.h>

#define NROWS (512 * 512)   // B*T = 262144
#define KCB   1024          // codebook size
#define DDIM  64            // embedding dim
#define TK    128           // k-tile staged in LDS (128*64*4B = 32 KB)
#define NQ    ((size_t)NROWS * DDIM)   // 16777216 floats of output 0

// B_k = sum_i weight[k][i]^2, fp32, numpy pairwise-8 pattern (bit-match np (w**2).sum(-1))
__global__ void wsq_kernel(const float* __restrict__ w, float* __restrict__ bsq) {
    int k = blockIdx.x * blockDim.x + threadIdx.x;
    if (k >= KCB) return;
    const float* row = w + (size_t)k * DDIM;
    float r[8];
#pragma unroll
    for (int j = 0; j < 8; ++j) r[j] = __fmul_rn(row[j], row[j]);
#pragma unroll
    for (int i = 8; i < DDIM; i += 8)
#pragma unroll
        for (int j = 0; j < 8; ++j)
            r[j] = __fadd_rn(r[j], __fmul_rn(row[i + j], row[i + j]));
    bsq[k] = __fadd_rn(__fadd_rn(__fadd_rn(r[0], r[1]), __fadd_rn(r[2], r[3])),
                       __fadd_rn(__fadd_rn(r[4], r[5]), __fadd_rn(r[6], r[7])));
}

__global__ __launch_bounds__(256, 2)
void vq_main(const float* __restrict__ h, const float* __restrict__ w,
             const float* __restrict__ bsq, float* __restrict__ out) {
    __shared__ float wl[TK * DDIM];   // 32 KB weight tile
    __shared__ float bl[TK];          // per-k squared norms

    const int tid = threadIdx.x;
    const size_t n = (size_t)blockIdx.x * 256 + tid;

    // h row -> 64 VGPRs
    const float* hrow = h + n * DDIM;
    float hr[DDIM];
#pragma unroll
    for (int i = 0; i < DDIM; i += 4) {
        float4 v = *reinterpret_cast<const float4*>(hrow + i);
        hr[i] = v.x; hr[i + 1] = v.y; hr[i + 2] = v.z; hr[i + 3] = v.w;
    }

    // A_n = (h**2).sum, numpy pairwise-8 ordering (bit-match np)
    float r[8];
#pragma unroll
    for (int j = 0; j < 8; ++j) r[j] = __fmul_rn(hr[j], hr[j]);
#pragma unroll
    for (int i = 8; i < DDIM; i += 8)
#pragma unroll
        for (int j = 0; j < 8; ++j)
            r[j] = __fadd_rn(r[j], __fmul_rn(hr[i + j], hr[i + j]));
    const float A = __fadd_rn(__fadd_rn(__fadd_rn(r[0], r[1]), __fadd_rn(r[2], r[3])),
                              __fadd_rn(__fadd_rn(r[4], r[5]), __fadd_rn(r[6], r[7])));

    float best = INFINITY;
    int bestk = 0;

#pragma unroll 1
    for (int t0 = 0; t0 < KCB; t0 += TK) {
        __syncthreads();
        // cooperative stage: 2048 float4s across 256 threads, coalesced
        const float4* wsrc = reinterpret_cast<const float4*>(w + (size_t)t0 * DDIM);
        float4* wdst = reinterpret_cast<float4*>(wl);
#pragma unroll
        for (int j = 0; j < 8; ++j) wdst[j * 256 + tid] = wsrc[j * 256 + tid];
        if (tid < TK) bl[tid] = bsq[t0 + tid];
        __syncthreads();

#pragma unroll 1
        for (int kq = 0; kq < TK; kq += 4) {
            float a0 = 0.f, a1 = 0.f, a2 = 0.f, a3 = 0.f;
            const float* w0p = wl + (kq + 0) * DDIM;
            const float* w1p = wl + (kq + 1) * DDIM;
            const float* w2p = wl + (kq + 2) * DDIM;
            const float* w3p = wl + (kq + 3) * DDIM;
#pragma unroll
            for (int i = 0; i < DDIM; i += 4) {
                float4 x0 = *reinterpret_cast<const float4*>(w0p + i);
                float4 x1 = *reinterpret_cast<const float4*>(w1p + i);
                float4 x2 = *reinterpret_cast<const float4*>(w2p + i);
                float4 x3 = *reinterpret_cast<const float4*>(w3p + i);
                // k-ascending single-accumulator FMA chains (bit-match BLAS sgemm microkernel)
                a0 = fmaf(hr[i + 0], x0.x, a0);
                a0 = fmaf(hr[i + 1], x0.y, a0);
                a0 = fmaf(hr[i + 2], x0.z, a0);
                a0 = fmaf(hr[i + 3], x0.w, a0);
                a1 = fmaf(hr[i + 0], x1.x, a1);
                a1 = fmaf(hr[i + 1], x1.y, a1);
                a1 = fmaf(hr[i + 2], x1.z, a1);
                a1 = fmaf(hr[i + 3], x1.w, a1);
                a2 = fmaf(hr[i + 0], x2.x, a2);
                a2 = fmaf(hr[i + 1], x2.y, a2);
                a2 = fmaf(hr[i + 2], x2.z, a2);
                a2 = fmaf(hr[i + 3], x2.w, a2);
                a3 = fmaf(hr[i + 0], x3.x, a3);
                a3 = fmaf(hr[i + 1], x3.y, a3);
                a3 = fmaf(hr[i + 2], x3.z, a3);
                a3 = fmaf(hr[i + 3], x3.w, a3);
            }
            // dist = fl(fl(A + B_k) - 2*acc); 2*acc (a+a) is exact
            float d0 = __fsub_rn(__fadd_rn(A, bl[kq + 0]), __fadd_rn(a0, a0));
            float d1 = __fsub_rn(__fadd_rn(A, bl[kq + 1]), __fadd_rn(a1, a1));
            float d2 = __fsub_rn(__fadd_rn(A, bl[kq + 2]), __fadd_rn(a2, a2));
            float d3 = __fsub_rn(__fadd_rn(A, bl[kq + 3]), __fadd_rn(a3, a3));
            // ascending-k, first-min-wins (matches np.argmin tie-break)
            if (d0 < best) { best = d0; bestk = t0 + kq + 0; }
            if (d1 < best) { best = d1; bestk = t0 + kq + 1; }
            if (d2 < best) { best = d2; bestk = t0 + kq + 2; }
            if (d3 < best) { best = d3; bestk = t0 + kq + 3; }
        }
    }

    // ---- epilogue: all outputs are FLOAT32 ----
    // gather winning codeword (weight is L2-resident, 256 KB), stream 8-wide:
    //   d = fl(q - h); qst = fl(h + d); r2[j] += fl(d*d) in numpy pairwise-8 slots
    const float* qrow = w + (size_t)bestk * DDIM;
    float* qst = out + n * DDIM;
    float r2[8];
#pragma unroll
    for (int c = 0; c < 8; ++c) {
        float4 qa = *reinterpret_cast<const float4*>(qrow + 8 * c);
        float4 qb = *reinterpret_cast<const float4*>(qrow + 8 * c + 4);
        float d0 = __fsub_rn(qa.x, hr[8 * c + 0]);
        float d1 = __fsub_rn(qa.y, hr[8 * c + 1]);
        float d2 = __fsub_rn(qa.z, hr[8 * c + 2]);
        float d3 = __fsub_rn(qa.w, hr[8 * c + 3]);
        float d4 = __fsub_rn(qb.x, hr[8 * c + 4]);
        float d5 = __fsub_rn(qb.y, hr[8 * c + 5]);
        float d6 = __fsub_rn(qb.z, hr[8 * c + 6]);
        float d7 = __fsub_rn(qb.w, hr[8 * c + 7]);
        if (c == 0) {
            r2[0] = __fmul_rn(d0, d0); r2[1] = __fmul_rn(d1, d1);
            r2[2] = __fmul_rn(d2, d2); r2[3] = __fmul_rn(d3, d3);
            r2[4] = __fmul_rn(d4, d4); r2[5] = __fmul_rn(d5, d5);
            r2[6] = __fmul_rn(d6, d6); r2[7] = __fmul_rn(d7, d7);
        } else {
            r2[0] = __fadd_rn(r2[0], __fmul_rn(d0, d0));
            r2[1] = __fadd_rn(r2[1], __fmul_rn(d1, d1));
            r2[2] = __fadd_rn(r2[2], __fmul_rn(d2, d2));
            r2[3] = __fadd_rn(r2[3], __fmul_rn(d3, d3));
            r2[4] = __fadd_rn(r2[4], __fmul_rn(d4, d4));
            r2[5] = __fadd_rn(r2[5], __fmul_rn(d5, d5));
            r2[6] = __fadd_rn(r2[6], __fmul_rn(d6, d6));
            r2[7] = __fadd_rn(r2[7], __fmul_rn(d7, d7));
        }
        float4 oa, ob;
        oa.x = __fadd_rn(hr[8 * c + 0], d0);
        oa.y = __fadd_rn(hr[8 * c + 1], d1);
        oa.z = __fadd_rn(hr[8 * c + 2], d2);
        oa.w = __fadd_rn(hr[8 * c + 3], d3);
        ob.x = __fadd_rn(hr[8 * c + 4], d4);
        ob.y = __fadd_rn(hr[8 * c + 5], d5);
        ob.z = __fadd_rn(hr[8 * c + 6], d6);
        ob.w = __fadd_rn(hr[8 * c + 7], d7);
        *reinterpret_cast<float4*>(qst + 8 * c) = oa;
        *reinterpret_cast<float4*>(qst + 8 * c + 4) = ob;
    }
    float S = __fadd_rn(__fadd_rn(__fadd_rn(r2[0], r2[1]), __fadd_rn(r2[2], r2[3])),
                        __fadd_rn(__fadd_rn(r2[4], r2[5]), __fadd_rn(r2[6], r2[7])));
    float m = __fmul_rn(S, 0.015625f);  // /64 exact
    float loss = __fadd_rn(__fmul_rn(m, 0.1f), __fmul_rn(m, 0.2f));

    // output 1: index as float32; output 2: loss as float32
    out[NQ + n] = (float)bestk;
    out[NQ + NROWS + n] = loss;
}

extern "C" void kernel_launch(void* const* d_in, const int* in_sizes, int n_in,
                              void* d_out, int out_size, void* d_ws, size_t ws_size,
                              hipStream_t stream) {
    (void)in_sizes; (void)n_in; (void)out_size; (void)ws_size;
    const float* h = (const float*)d_in[0];  // (262144, 64) f32
    const float* w = (const float*)d_in[1];  // (1024, 64) f32
    float* bsq = (float*)d_ws;               // 4 KB scratch
    float* out = (float*)d_out;              // f32: [quantized_st][indices][loss]

    wsq_kernel<<<(KCB + 255) / 256, 256, 0, stream>>>(w, bsq);
    vq_main<<<NROWS / 256, 256, 0, stream>>>(h, w, bsq, out);
}